// Round 11
// baseline (281.913 us; speedup 1.0000x reference)
//
#include <hip/hip_runtime.h>

typedef __attribute__((ext_vector_type(8))) short   short8;
typedef __attribute__((ext_vector_type(8))) __bf16  bf16x8;
typedef __attribute__((ext_vector_type(4))) __bf16  bf16x4;
typedef __attribute__((ext_vector_type(4))) float   f32x4;
typedef __attribute__((ext_vector_type(4))) unsigned short ushort4v;

#define NSTEPS 49

static __device__ __forceinline__ short8 as_s8(bf16x8 v) {
    return __builtin_bit_cast(short8, v);
}
static __device__ __forceinline__ bf16x4 pack4(f32x4 v) {
    bf16x4 b;
    b[0] = (__bf16)v[0]; b[1] = (__bf16)v[1];
    b[2] = (__bf16)v[2]; b[3] = (__bf16)v[3];
    return b;
}

#define MFMA(A, B, C) __builtin_amdgcn_mfma_f32_16x16x32_bf16((A), (B), (C), 0, 0, 0)

// Third L1 K-slice: slot (q=0,j=0) carries t, (q=0,j=1) carries 1.0 (bias col).
#define BUILD_XT(TV)                                                         \
    {                                                                        \
        bf16x8 v_;                                                           \
        _Pragma("unroll") for (int j_ = 0; j_ < 8; ++j_) v_[j_] = (__bf16)0.f; \
        if (q == 0) { v_[0] = (__bf16)(TV); v_[1] = (__bf16)1.0f; }          \
        xt = as_s8(v_);                                                      \
    }

#define RELU_PACK(AA, AB, OUT)                                               \
    {                                                                        \
        bf16x8 v_;                                                           \
        v_[0]=(__bf16)fmaxf((AA)[0],0.f); v_[1]=(__bf16)fmaxf((AA)[1],0.f);  \
        v_[2]=(__bf16)fmaxf((AA)[2],0.f); v_[3]=(__bf16)fmaxf((AA)[3],0.f);  \
        v_[4]=(__bf16)fmaxf((AB)[0],0.f); v_[5]=(__bf16)fmaxf((AB)[1],0.f);  \
        v_[6]=(__bf16)fmaxf((AB)[2],0.f); v_[7]=(__bf16)fmaxf((AB)[3],0.f);  \
        OUT = as_s8(v_);                                                     \
    }

// One Tsit5 stage, 2 barriers, ONE exposed LDS latency (the g-read).
// L1 is computed REDUNDANTLY by all 4 waves (R10 lesson applied to the
// right layer): the packed L1 C-outputs ARE the L2 B-frags (verified
// K-permutation bit-exactness), so L2 consumes registers — the h-exchange
// (ds_write+barrier+120cyc ds_read) is deleted at the cost of +22 MFMA
// issue (~110 cyc). L2/L3 stay tile-split so the per-wave state tail stays
// 4 dims (R10's 16-dim redundant tail was the regression). The next-stage
// xs read is hoisted to right after barrier-2 so the register-only state
// tail hides its latency.
#define STAGE(TN, HS)                                                        \
    {                                                                        \
        const f32x4 zz = {0.f, 0.f, 0.f, 0.f};                               \
        short8 xt; BUILD_XT(TN);                                             \
        /* ---- P1: L1 ALL 8 tiles (xs in registers) -> xh frags in reg ---- */ \
        short8 xh_[4];                                                       \
        _Pragma("unroll")                                                    \
        for (int p_ = 0; p_ < 4; ++p_) {                                     \
            f32x4 aA_ = MFMA(wL1a[6*p_ + 0], xs0, zz);                       \
            aA_ = MFMA(wL1a[6*p_ + 1], xs1, aA_);                            \
            aA_ = MFMA(wL1a[6*p_ + 2], xt,  aA_);                            \
            f32x4 aB_ = MFMA(wL1a[6*p_ + 3], xs0, zz);                       \
            aB_ = MFMA(wL1a[6*p_ + 4], xs1, aB_);                            \
            aB_ = MFMA(wL1a[6*p_ + 5], xt,  aB_);                            \
            RELU_PACK(aA_, aB_, xh_[p_]);                                    \
        }                                                                    \
        /* ---- P2: L2 own tiles 2w,2w+1 from REGISTER xh (no LDS) ---- */   \
        f32x4 gA = MFMA(wL2[0], xh_[0], bL2v[0]); gA = MFMA(wL2[1], xh_[1], gA); \
        gA = MFMA(wL2[2], xh_[2], gA);            gA = MFMA(wL2[3], xh_[3], gA); \
        f32x4 gB = MFMA(wL2[4], xh_[0], bL2v[1]); gB = MFMA(wL2[5], xh_[1], gB); \
        gB = MFMA(wL2[6], xh_[2], gB);            gB = MFMA(wL2[7], xh_[3], gB); \
        short8 xgm; RELU_PACK(gA, gB, xgm);                                  \
        *(short8*)(&XG[w][lane][0]) = xgm;                                   \
        __syncthreads();                                                     \
        /* ---- P3: L3 own tile w; si = pre + h*kv; exchange si ---- */      \
        short8 xg0 = *(const short8*)(&XG[0][lane][0]);                      \
        short8 xg1 = *(const short8*)(&XG[1][lane][0]);                      \
        short8 xg2 = *(const short8*)(&XG[2][lane][0]);                      \
        short8 xg3 = *(const short8*)(&XG[3][lane][0]);                      \
        kv = MFMA(wL3[0], xg0, bL3v); kv = MFMA(wL3[1], xg1, kv);            \
        kv = MFMA(wL3[2], xg2, kv);   kv = MFMA(wL3[3], xg3, kv);            \
        _Pragma("unroll")                                                    \
        for (int r_ = 0; r_ < 4; ++r_) si[r_] = pre[r_] + (HS) * kv[r_];     \
        *(ushort4v*)(&XS[w >> 1][lane][4 * (w & 1)]) =                       \
            __builtin_bit_cast(ushort4v, pack4(si));                        \
        __syncthreads();                                                     \
        /* next-stage xs read issues NOW; state tail hides its latency */    \
        xs0 = *(const short8*)(&XS[0][lane][0]);                             \
        xs1 = *(const short8*)(&XS[1][lane][0]);                             \
    }

// 128 blocks x 4 waves; one 16-row system per block (max batch parallelism).
// Wave w: ALL of L1 (24 frags, 96 VGPR), L2 tiles 2w,2w+1 (32), L3 tile w
// (16) + 4-dim/lane state. 2 barriers/stage, 1 exposed ds_read latency.
extern "C" __global__ void __launch_bounds__(256, 1)
node_solve(const float* __restrict__ y0, const float* __restrict__ ts,
           const float* __restrict__ gw0, const float* __restrict__ gb0,
           const float* __restrict__ gw1, const float* __restrict__ gb1,
           const float* __restrict__ gw2, const float* __restrict__ gb2,
           float* __restrict__ out)
{
    __shared__ __align__(16) unsigned short XS[2][64][8];  // stage-input slices
    __shared__ __align__(16) unsigned short XG[4][64][8];  // L2 out slices

    const int tid  = threadIdx.x;
    const int w    = tid >> 6;      // wave 0..3
    const int lane = tid & 63;
    const int q    = lane >> 4;
    const int c    = lane & 15;
    const int row0 = blockIdx.x << 4;

    // ---- weights -> K-permuted register A-frags ----
    // perm: k-position (ks, q, j) <- source column 32ks+16*(j>>2)+4q+(j&3)
    short8 wL1a[24];  // ALL 8 tiles x {y0-31, y32-63, [t,bias]} (redundant)
    short8 wL2[8];    // own tiles 2w,2w+1 x 4 k-slices
    short8 wL3[4];    // own tile w x 4 k-slices
    f32x4  bL2v[2], bL3v;

    #pragma unroll
    for (int t = 0; t < 8; ++t) {
        const int n = 16 * t + c;
        const float* w0r = gw0 + n * 65 + 1;      // col 0 of gw0 is the t-weight
        #pragma unroll
        for (int ks = 0; ks < 2; ++ks) {
            bf16x8 v;
            #pragma unroll
            for (int j = 0; j < 8; ++j)
                v[j] = (__bf16)w0r[32*ks + 16*(j>>2) + 4*q + (j&3)];
            wL1a[3*t + ks] = as_s8(v);
        }
        {
            bf16x8 v;
            #pragma unroll
            for (int j = 0; j < 8; ++j) v[j] = (__bf16)0.f;
            if (q == 0) { v[0] = (__bf16)gw0[n*65]; v[1] = (__bf16)gb0[n]; }
            wL1a[3*t + 2] = as_s8(v);
        }
    }
    #pragma unroll
    for (int p = 0; p < 2; ++p) {
        const int t = 2 * w + p;
        const int n = 16 * t + c;
        const float* w1r = gw1 + n * 128;
        #pragma unroll
        for (int ks = 0; ks < 4; ++ks) {
            bf16x8 v;
            #pragma unroll
            for (int j = 0; j < 8; ++j)
                v[j] = (__bf16)w1r[32*ks + 16*(j>>2) + 4*q + (j&3)];
            wL2[4*p + ks] = as_s8(v);
        }
        bL2v[p] = *(const f32x4*)(gb1 + 16*t + 4*q);
    }
    {
        const int n = 16 * w + c;
        const float* w2r = gw2 + n * 128;
        #pragma unroll
        for (int ks = 0; ks < 4; ++ks) {
            bf16x8 v;
            #pragma unroll
            for (int j = 0; j < 8; ++j)
                v[j] = (__bf16)w2r[32*ks + 16*(j>>2) + 4*q + (j&3)];
            wL3[ks] = as_s8(v);
        }
        bL3v = *(const f32x4*)(gb2 + 16*w + 4*q);
    }

    // ---- ODE state: this wave owns dims 16w+4q+r of batch row row0+c ----
    f32x4 yn = *(const f32x4*)(y0 + (size_t)(row0 + c) * 64 + 16*w + 4*q);

    const float ts0 = ts[0];
    const float dtv = ts[1] - ts[0];

    // dt-scaled Tsit5: e = dt*b, h_s = dt*a_{s+1,s}, g_sj = dt*(a_sj - b_j)
    const float e1 = dtv * 0.09646076681806523f, e2 = dtv * 0.01f;
    const float e3 = dtv * 0.4798896504144996f,  e4 = dtv * 1.379008574103742f;
    const float e5 = dtv * -3.290069515436081f,  e6 = dtv * 2.324710524099774f;
    const float h0 = dtv * 0.161f;
    const float h1 = dtv * 0.335480655492357f;
    const float h2 = dtv * 4.3622954328695815f;
    const float h3 = dtv * -0.09249506636175525f;
    const float h4 = dtv * -0.028269050394068383f;
    const float g31 = dtv * (-0.008480655492356989f - 0.09646076681806523f);
    const float g41 = dtv * (2.8971530571054935f    - 0.09646076681806523f);
    const float g42 = dtv * (-6.359448489975075f    - 0.01f);
    const float g51 = dtv * (5.325864828439257f     - 0.09646076681806523f);
    const float g52 = dtv * (-11.748883564062828f   - 0.01f);
    const float g53 = dtv * (7.4955393428898365f    - 0.4798896504144996f);
    const float g61 = dtv * (5.86145544294642f      - 0.09646076681806523f);
    const float g62 = dtv * (-12.92096931784711f    - 0.01f);
    const float g63 = dtv * (8.159367898576159f     - 0.4798896504144996f);
    const float g64 = dtv * (-0.071584973281401f    - 1.379008574103742f);

    // ---- initial stage input si1 = y0 -> XS; pre for si2 = y0 ----
    *(ushort4v*)(&XS[w >> 1][lane][4 * (w & 1)]) =
        __builtin_bit_cast(ushort4v, pack4(yn));
    f32x4 pre = yn, si, kv;
    __syncthreads();
    short8 xs0 = *(const short8*)(&XS[0][lane][0]);
    short8 xs1 = *(const short8*)(&XS[1][lane][0]);

    #pragma unroll 1
    for (int step = 0; step < NSTEPS; ++step) {
        const float t0s = ts0 + (float)step * dtv;
        bf16x4 kb0, kb1, kb2, kb3;

        // ---- stage 1 ----  (tail after barrier: register-only, hides xs read)
        STAGE(t0s, h0)
        #pragma unroll
        for (int r = 0; r < 4; ++r) yn[r] += e1 * kv[r];
        kb0 = pack4(kv);
        #pragma unroll
        for (int r = 0; r < 4; ++r) pre[r] = yn[r] + g31 * (float)kb0[r];

        // ---- stage 2 ----
        STAGE(t0s + 0.161f * dtv, h1)
        #pragma unroll
        for (int r = 0; r < 4; ++r) yn[r] += e2 * kv[r];
        kb1 = pack4(kv);
        #pragma unroll
        for (int r = 0; r < 4; ++r)
            pre[r] = yn[r] + g41 * (float)kb0[r] + g42 * (float)kb1[r];

        // ---- stage 3 ----
        STAGE(t0s + 0.327f * dtv, h2)
        #pragma unroll
        for (int r = 0; r < 4; ++r) yn[r] += e3 * kv[r];
        kb2 = pack4(kv);
        #pragma unroll
        for (int r = 0; r < 4; ++r)
            pre[r] = yn[r] + g51 * (float)kb0[r] + g52 * (float)kb1[r]
                   + g53 * (float)kb2[r];

        // ---- stage 4 ----
        STAGE(t0s + 0.9f * dtv, h3)
        #pragma unroll
        for (int r = 0; r < 4; ++r) yn[r] += e4 * kv[r];
        kb3 = pack4(kv);
        #pragma unroll
        for (int r = 0; r < 4; ++r)
            pre[r] = yn[r] + g61 * (float)kb0[r] + g62 * (float)kb1[r]
                   + g63 * (float)kb2[r] + g64 * (float)kb3[r];

        // ---- stage 5 ----
        STAGE(t0s + 0.9800255409045097f * dtv, h4)
        #pragma unroll
        for (int r = 0; r < 4; ++r) { yn[r] += e5 * kv[r]; pre[r] = yn[r]; }

        // ---- stage 6: si = yn + e6*kv = new y (exact f32 carry) ----
        STAGE(t0s + dtv, e6)
        #pragma unroll
        for (int r = 0; r < 4; ++r) { yn[r] = si[r]; pre[r] = si[r]; }
    }

    // ---- output: this wave's dims of row row0+c ----
    *(f32x4*)(&out[(size_t)(row0 + c) * 64 + 16*w + 4*q]) = yn;
}

extern "C" void kernel_launch(void* const* d_in, const int* in_sizes, int n_in,
                              void* d_out, int out_size, void* d_ws, size_t ws_size,
                              hipStream_t stream) {
    const float* y0 = (const float*)d_in[0];
    const float* ts = (const float*)d_in[1];
    const float* w0 = (const float*)d_in[2];
    const float* b0 = (const float*)d_in[3];
    const float* w1 = (const float*)d_in[4];
    const float* b1 = (const float*)d_in[5];
    const float* w2 = (const float*)d_in[6];
    const float* b2 = (const float*)d_in[7];
    float* out = (float*)d_out;

    node_solve<<<dim3(128), dim3(256), 0, stream>>>(y0, ts, w0, b0, w1, b1, w2, b2, out);
}